// Round 10
// baseline (567.198 us; speedup 1.0000x reference)
//
#include <hip/hip_runtime.h>

#define SEQ 2048
#define BATCH 16
#define DMODEL 512
#define FFDIM 2048
#define NTOK (SEQ * BATCH) /* 32768 tokens */
#define ALPHA 0.9f

typedef unsigned short u16;
typedef unsigned int u32;
typedef __attribute__((ext_vector_type(8))) short short8;
typedef __attribute__((ext_vector_type(4))) float f32x4;

__device__ __forceinline__ float bf2f(u16 u) {
    unsigned int v = ((unsigned int)u) << 16;
    return __builtin_bit_cast(float, v);
}
__device__ __forceinline__ u16 f2bf(float f) {
    unsigned int v = __builtin_bit_cast(unsigned int, f);
    v += 0x7fffu + ((v >> 16) & 1u);   // RNE
    return (u16)(v >> 16);
}

// ---------------------------------------------------------------------------
// fp32 -> bf16 conversion (weights), 4 elems/thread
// ---------------------------------------------------------------------------
__global__ __launch_bounds__(256) void cvt_kernel(const float* __restrict__ in,
                                                  u16* __restrict__ out, int n) {
    const int i = (blockIdx.x * 256 + threadIdx.x) * 4;
    if (i >= n) return;
    float4 v = *(const float4*)(in + i);
    ushort4 o;
    o.x = f2bf(v.x); o.y = f2bf(v.y); o.z = f2bf(v.z); o.w = f2bf(v.w);
    *(ushort4*)(out + i) = o;
}

// ---------------------------------------------------------------------------
// LayerNorm: one wave per token (64 lanes x 8 elems = 512 = DMODEL)
// ---------------------------------------------------------------------------
__global__ __launch_bounds__(256) void ln_kernel(const float* __restrict__ xin,
                                                 const float* __restrict__ g,
                                                 const float* __restrict__ b,
                                                 u16* __restrict__ y) {
    const int lane = threadIdx.x & 63;
    const int wave = threadIdx.x >> 6;
    const long tok = (long)blockIdx.x * 4 + wave;
    const long off = tok * DMODEL + lane * 8;

    float f[8];
    {
        const float4* xp = (const float4*)(xin + off);
        float4 a = xp[0], c = xp[1];
        f[0] = a.x; f[1] = a.y; f[2] = a.z; f[3] = a.w;
        f[4] = c.x; f[5] = c.y; f[6] = c.z; f[7] = c.w;
    }
    float s = 0.f, s2 = 0.f;
#pragma unroll
    for (int i = 0; i < 8; i++) { s += f[i]; s2 += f[i] * f[i]; }
#pragma unroll
    for (int o = 32; o > 0; o >>= 1) {
        s += __shfl_xor(s, o, 64);
        s2 += __shfl_xor(s2, o, 64);
    }
    const float mean = s * (1.f / DMODEL);
    const float var = s2 * (1.f / DMODEL) - mean * mean;
    const float inv = rsqrtf(var + 1e-5f);

    const float4* gp = (const float4*)(g + lane * 8);
    const float4* bp = (const float4*)(b + lane * 8);
    float4 g0 = gp[0], g1 = gp[1], b0 = bp[0], b1 = bp[1];
    float gg[8] = {g0.x, g0.y, g0.z, g0.w, g1.x, g1.y, g1.z, g1.w};
    float bb[8] = {b0.x, b0.y, b0.z, b0.w, b1.x, b1.y, b1.z, b1.w};
    short8 ov;
#pragma unroll
    for (int i = 0; i < 8; i++)
        ov[i] = (short)f2bf((f[i] - mean) * inv * gg[i] + bb[i]);
    *(short8*)(y + off) = ov;
}

// ---------------------------------------------------------------------------
// Causal exp-decay scan, barrier-free, column-parallel (verified round 5).
// ---------------------------------------------------------------------------
#define SCAN_L 64
#define SCAN_H 128
#define NCOLU (BATCH * DMODEL / 2) /* 4096 u32 columns, row stride 4096 */
__global__ __launch_bounds__(256) void scan_kernel(const u16* __restrict__ z,
                                                   const float* __restrict__ x,
                                                   float* __restrict__ x1) {
    const int colu = blockIdx.x * 256 + threadIdx.x;  // 0..4095
    const int s0 = blockIdx.y * SCAN_L;

    const u32* zp = (const u32*)z;
    const float2* xp = (const float2*)x;
    float2* x1p = (float2*)x1;

    float r0 = 0.f, r1 = 0.f;

    // ---- warm-up: runtime-bounded (nw in {0,64,128}), 4-deep prefetch ----
    {
        int sb = s0 - SCAN_H;
        if (sb < 0) sb = 0;
        const int nw = s0 - sb;
        if (nw > 0) {  // nw >= 64, multiple of 4
            u32 zq[4];
#pragma unroll
            for (int j = 0; j < 4; j++) zq[j] = zp[(long)(sb + j) * NCOLU + colu];
            for (int i = 0; i < nw; i += 4) {
#pragma unroll
                for (int j = 0; j < 4; j++) {
                    const u32 zz = zq[j];
                    if (i + j + 4 < nw)
                        zq[j] = zp[(long)(sb + i + j + 4) * NCOLU + colu];
                    r0 = ALPHA * (bf2f((u16)(zz & 0xffffu)) + r0);
                    r1 = ALPHA * (bf2f((u16)(zz >> 16)) + r1);
                }
            }
        }
    }

    float ap = powf(ALPHA, (float)(s0 + 2));  // alpha^{s0+2}

    // ---- main: 4-deep prefetch of z and x (fixed trip count) ----
    u32 zq[4];
    float2 xq[4];
#pragma unroll
    for (int j = 0; j < 4; j++) {
        zq[j] = zp[(long)(s0 + j) * NCOLU + colu];
        xq[j] = xp[(long)(s0 + j) * NCOLU + colu];
    }
#pragma unroll 4
    for (int i = 0; i < SCAN_L; i++) {
        const int sl = i & 3;  // compile-time per unrolled instance
        const u32 zz = zq[sl];
        const float2 xx = xq[sl];
        if (i + 4 < SCAN_L) {
            zq[sl] = zp[(long)(s0 + i + 4) * NCOLU + colu];
            xq[sl] = xp[(long)(s0 + i + 4) * NCOLU + colu];
        }
        const float z0 = bf2f((u16)(zz & 0xffffu));
        const float z1 = bf2f((u16)(zz >> 16));
        r0 = ALPHA * (z0 + r0);
        r1 = ALPHA * (z1 + r1);
        const float c = 1.f - (ALPHA - ap) * 10.f;  // 10 = 1/(1-alpha)
        ap *= ALPHA;
        x1p[(long)(s0 + i) * NCOLU + colu] = (float2){xx.x + r0 + c * z0, xx.y + r1 + c * z1};
    }
}

// ---------------------------------------------------------------------------
// GEMM 128x256 / BK=64 / 8 waves / A-only LDS, B direct from L2.
//   C[M,N] = epi(A[M,K] @ Bt[N,K]^T + bias[N])
// Round-10: B is always an L2-resident weight (0.5-2 MB) -> staging it through
// LDS doubles gld_lds volume + LDS size for zero HBM benefit. A-only LDS =
// 32 KiB -> 2 blocks/CU (16 waves, 4/SIMD) at 512-2048-block grids; B-frags
// are short8 global loads the compiler prefetches across the unbarriered MFMA
// block. Simple 2-barrier loop (r9: thin phases hurt).
// vmcnt ledger: STG_A(t+1) = 2 loads; at vmcnt(2) outstanding = A(t)(2 old) +
// A(t+1)(2 new) -> retires A(t). bf loads issue AFTER the vmcnt so they never
// pollute the count; compiler waits its own bf loads before their MFMA use,
// so all bf are retired before the next iteration's vmcnt. Last tile vmcnt(0).
// Swizzle (r5-proven, 0 conflicts): stage source octet c=(o&3)^((o>>3)&3)
// (= oct ^ ((row>>1)&3), row=o>>2); read octet q16 ^ ((l15>>1)&3); fragment
// rows === l15 (mod 16) -> involution = identity, 2 lanes/16B slot = free.
// XCD decode (verified r5): d=bx+by*gx; wgid=(d&7)*(nwg/8)+(d>>3);
// m0=wgid/gy (n-fastest) -> A-panel fetched once per XCD, L2-shared.
// EPI: 0=+bias  1=relu(+bias)  2=+bias+resid(fp32);  OUT_F32 selects store type
// ---------------------------------------------------------------------------
#define BM 128
#define BN 256
#define BKK 64

typedef __attribute__((address_space(1))) unsigned int as1_u32;
typedef __attribute__((address_space(3))) unsigned int as3_u32;

__device__ __forceinline__ void gld_lds16(const void* g, const void* l) {
    __builtin_amdgcn_global_load_lds((as1_u32*)(unsigned long long)g,
                                     (as3_u32*)(unsigned int)(unsigned long long)l,
                                     16, 0, 0);
}

template <int EPI, bool OUT_F32>
__global__ __launch_bounds__(512, 4) void gemm_bl2(const u16* __restrict__ A,
                                                   const u16* __restrict__ Bt,
                                                   const float* __restrict__ bias,
                                                   const float* __restrict__ resid,
                                                   void* __restrict__ C,
                                                   int M, int N, int K) {
    __shared__ alignas(16) u16 sA[2][2][128 * 32];  // [dbuf][kk-half][row*32k] 32 KiB

    const int tid = threadIdx.x;
    const int lane = tid & 63;
    const int wave = tid >> 6;      // 8 waves: 2M x 4N, each owns 64x64
    const int wr = wave >> 2;       // 0..1  (64-token half)
    const int wc = wave & 3;        // 0..3  (64-col quarter)
    const int l15 = lane & 15, q16 = lane >> 4;

    // dispatch-anchored bijective XCD swizzle; n-fastest within an XCD chunk
    const int gy = gridDim.y;
    const int nwg = gridDim.x * gy;
    const int d = blockIdx.y * gridDim.x + blockIdx.x;  // HW dispatch order
    const int wgid = (d & 7) * (nwg >> 3) + (d >> 3);
    const int m0 = (wgid / gy) * BM;
    const int n0 = (wgid % gy) * BN;

    // ---- A staging: half-tile [128 rows][32 k] = 512 octets; 512 threads ->
    //      1 octet each. o=tid: row=o>>2, dest slot o (linear, m104),
    //      source octet c = (o&3) ^ ((row>>1)&3) = (o&3)^((o>>3)&3). ----
    const int c = (tid & 3) ^ ((tid >> 3) & 3);
    const u16* gA0 = A + (long)(m0 + (tid >> 2)) * K + c * 8;
    u16* dst0 = &sA[0][0][tid * 8];
    const int dbufStride = 2 * 128 * 32;  // elems between sA[0] and sA[1]

    // ---- fragment read addressing (r5 zero-conflict swizzle) ----
    const int xoct = (q16 ^ ((l15 >> 1) & 3)) * 8;
    // B direct: per-lane row base; nj/kk/k-tile offsets are wave-uniform scalars
    const u16* gB0 = Bt + (long)(n0 + wc * 64 + l15) * K + q16 * 8;

    f32x4 acc[4][4];
#pragma unroll
    for (int i = 0; i < 4; i++)
#pragma unroll
        for (int j = 0; j < 4; j++) acc[i][j] = (f32x4){0.f, 0.f, 0.f, 0.f};

    const int NT = K / BKK;

#define STG_A(bs, koff)                                                     \
    {                                                                       \
        gld_lds16(gA0 + (koff), dst0 + (bs)*dbufStride);                    \
        gld_lds16(gA0 + (koff) + 32, dst0 + (bs)*dbufStride + 128 * 32);    \
    }

    // prologue: stage tile 0 -> buf 0 (2 loads in flight)
    STG_A(0, 0);

#pragma unroll 1
    for (int t = 0; t < NT; ++t) {
        const int b = t & 1, bn = b ^ 1;
        const bool nx = (t + 1 < NT);
        if (nx) {
            STG_A(bn, (t + 1) * BKK);
            asm volatile("s_waitcnt vmcnt(2)" ::: "memory");  // tile t landed
        } else {
            asm volatile("s_waitcnt vmcnt(0)" ::: "memory");
        }
        __builtin_amdgcn_s_barrier();   // all waves' tile-t loads landed

#pragma unroll
        for (int kk = 0; kk < 2; kk++) {
            // B fragments straight from global (L2-resident weight)
            short8 bf[4];
#pragma unroll
            for (int nj = 0; nj < 4; nj++)
                bf[nj] = *(const short8*)(gB0 + (long)nj * 16 * K + t * BKK + kk * 32);
            // A fragments from LDS (swizzled)
            short8 af[4];
#pragma unroll
            for (int mi = 0; mi < 4; mi++)
                af[mi] = *(const short8*)(&sA[b][kk][(wr * 64 + mi * 16 + l15) * 32 + xoct]);
#pragma unroll
            for (int mi = 0; mi < 4; mi++)
#pragma unroll
                for (int nj = 0; nj < 4; nj++)
                    acc[mi][nj] = __builtin_amdgcn_mfma_f32_16x16x32_bf16(af[mi], bf[nj],
                                                                          acc[mi][nj], 0, 0, 0);
        }
        __builtin_amdgcn_s_barrier();   // readers done before buf[b] restage
    }
#undef STG_A

    // ---- epilogue: C/D layout col=lane&15, row=(lane>>4)*4+reg ----
#pragma unroll
    for (int mi = 0; mi < 4; mi++) {
        const int row0 = m0 + wr * 64 + mi * 16 + q16 * 4;
#pragma unroll
        for (int nj = 0; nj < 4; nj++) {
            const int col = n0 + wc * 64 + nj * 16 + l15;
            const float bv = bias[col];
#pragma unroll
            for (int r = 0; r < 4; r++) {
                const long idx = (long)(row0 + r) * N + col;
                float v = acc[mi][nj][r] + bv;
                if (EPI == 1) v = fmaxf(v, 0.f);
                if (EPI == 2) v += resid[idx];
                if (OUT_F32)
                    ((float*)C)[idx] = v;
                else
                    ((u16*)C)[idx] = f2bf(v);
            }
        }
    }
}

// ---------------------------------------------------------------------------
extern "C" void kernel_launch(void* const* d_in, const int* in_sizes, int n_in,
                              void* d_out, int out_size, void* d_ws, size_t ws_size,
                              hipStream_t stream) {
    const float* x = (const float*)d_in[0];
    const float* w_lin = (const float*)d_in[1];
    const float* b_lin = (const float*)d_in[2];
    const float* w1 = (const float*)d_in[3];
    const float* b1 = (const float*)d_in[4];
    const float* w2 = (const float*)d_in[5];
    const float* b2 = (const float*)d_in[6];
    const float* g1 = (const float*)d_in[7];
    const float* be1 = (const float*)d_in[8];
    const float* g2 = (const float*)d_in[9];
    const float* be2 = (const float*)d_in[10];
    float* out = (float*)d_out;

    char* ws = (char*)d_ws;
    const size_t MB = 1024 * 1024;
    u16* y = (u16*)(ws);                       // LN output bf16, 32 MB
    float* x1 = (float*)(ws + 32 * MB);        // attn residual fp32, 64 MB
    u16* h = (u16*)(ws + 96 * MB);             // FF hidden bf16, 128 MB
    u16* z = h;                                // projection bf16, 32 MB (aliases h; z dies before h is written)
    u16* wb_lin = (u16*)(ws + 224 * MB);       // bf16 weights
    u16* wb1 = (u16*)(ws + 225 * MB);
    u16* wb2 = (u16*)(ws + 228 * MB);

    // 0) convert weights fp32 -> bf16
    cvt_kernel<<<(DMODEL * DMODEL) / 1024, 256, 0, stream>>>(w_lin, wb_lin, DMODEL * DMODEL);
    cvt_kernel<<<(FFDIM * DMODEL) / 1024, 256, 0, stream>>>(w1, wb1, FFDIM * DMODEL);
    cvt_kernel<<<(DMODEL * FFDIM) / 1024, 256, 0, stream>>>(w2, wb2, DMODEL * FFDIM);

    // 1) y = LN(x; g1, be1)
    ln_kernel<<<NTOK / 4, 256, 0, stream>>>(x, g1, be1, y);
    // 2) z = y @ w_lin^T + b_lin   (grid 256x2 = 512 blocks)
    gemm_bl2<0, false><<<dim3(NTOK / BM, DMODEL / BN), 512, 0, stream>>>(y, wb_lin, b_lin,
                                                                        nullptr, z,
                                                                        NTOK, DMODEL, DMODEL);
    // 3) x1 = x + W @ z   (exp-decay scan)
    scan_kernel<<<dim3(NCOLU / 256, SEQ / SCAN_L), 256, 0, stream>>>(z, x, x1);
    // 4) y = LN(x1; g2, be2)
    ln_kernel<<<NTOK / 4, 256, 0, stream>>>(x1, g2, be2, y);
    // 5) h = relu(y @ w1^T + b1)   (grid 256x8 = 2048 blocks)
    gemm_bl2<1, false><<<dim3(NTOK / BM, FFDIM / BN), 512, 0, stream>>>(y, wb1, b1, nullptr, h,
                                                                       NTOK, FFDIM, DMODEL);
    // 6) out = x1 + h @ w2^T + b2  (grid 256x2 = 512 blocks)
    gemm_bl2<2, true><<<dim3(NTOK / BM, DMODEL / BN), 512, 0, stream>>>(h, wb2, b2, x1, out,
                                                                       NTOK, DMODEL, FFDIM);
}

// Round 11
// 429.580 us; speedup vs baseline: 1.3204x; 1.3204x over previous
//
#include <hip/hip_runtime.h>

#define SEQ 2048
#define BATCH 16
#define DMODEL 512
#define FFDIM 2048
#define NTOK (SEQ * BATCH) /* 32768 tokens */
#define ALPHA 0.9f

typedef unsigned short u16;
typedef unsigned int u32;
typedef __attribute__((ext_vector_type(8))) short short8;
typedef __attribute__((ext_vector_type(4))) float f32x4;

__device__ __forceinline__ float bf2f(u16 u) {
    unsigned int v = ((unsigned int)u) << 16;
    return __builtin_bit_cast(float, v);
}
__device__ __forceinline__ u16 f2bf(float f) {
    unsigned int v = __builtin_bit_cast(unsigned int, f);
    v += 0x7fffu + ((v >> 16) & 1u);   // RNE
    return (u16)(v >> 16);
}

// ---------------------------------------------------------------------------
// fp32 -> bf16 conversion (weights), 4 elems/thread
// ---------------------------------------------------------------------------
__global__ __launch_bounds__(256) void cvt_kernel(const float* __restrict__ in,
                                                  u16* __restrict__ out, int n) {
    const int i = (blockIdx.x * 256 + threadIdx.x) * 4;
    if (i >= n) return;
    float4 v = *(const float4*)(in + i);
    ushort4 o;
    o.x = f2bf(v.x); o.y = f2bf(v.y); o.z = f2bf(v.z); o.w = f2bf(v.w);
    *(ushort4*)(out + i) = o;
}

// ---------------------------------------------------------------------------
// LayerNorm: one wave per token (64 lanes x 8 elems = 512 = DMODEL)
// ---------------------------------------------------------------------------
__global__ __launch_bounds__(256) void ln_kernel(const float* __restrict__ xin,
                                                 const float* __restrict__ g,
                                                 const float* __restrict__ b,
                                                 u16* __restrict__ y) {
    const int lane = threadIdx.x & 63;
    const int wave = threadIdx.x >> 6;
    const long tok = (long)blockIdx.x * 4 + wave;
    const long off = tok * DMODEL + lane * 8;

    float f[8];
    {
        const float4* xp = (const float4*)(xin + off);
        float4 a = xp[0], c = xp[1];
        f[0] = a.x; f[1] = a.y; f[2] = a.z; f[3] = a.w;
        f[4] = c.x; f[5] = c.y; f[6] = c.z; f[7] = c.w;
    }
    float s = 0.f, s2 = 0.f;
#pragma unroll
    for (int i = 0; i < 8; i++) { s += f[i]; s2 += f[i] * f[i]; }
#pragma unroll
    for (int o = 32; o > 0; o >>= 1) {
        s += __shfl_xor(s, o, 64);
        s2 += __shfl_xor(s2, o, 64);
    }
    const float mean = s * (1.f / DMODEL);
    const float var = s2 * (1.f / DMODEL) - mean * mean;
    const float inv = rsqrtf(var + 1e-5f);

    const float4* gp = (const float4*)(g + lane * 8);
    const float4* bp = (const float4*)(b + lane * 8);
    float4 g0 = gp[0], g1 = gp[1], b0 = bp[0], b1 = bp[1];
    float gg[8] = {g0.x, g0.y, g0.z, g0.w, g1.x, g1.y, g1.z, g1.w};
    float bb[8] = {b0.x, b0.y, b0.z, b0.w, b1.x, b1.y, b1.z, b1.w};
    short8 ov;
#pragma unroll
    for (int i = 0; i < 8; i++)
        ov[i] = (short)f2bf((f[i] - mean) * inv * gg[i] + bb[i]);
    *(short8*)(y + off) = ov;
}

// ---------------------------------------------------------------------------
// Causal exp-decay scan, barrier-free, column-parallel (verified round 5).
// ---------------------------------------------------------------------------
#define SCAN_L 64
#define SCAN_H 128
#define NCOLU (BATCH * DMODEL / 2) /* 4096 u32 columns, row stride 4096 */
__global__ __launch_bounds__(256) void scan_kernel(const u16* __restrict__ z,
                                                   const float* __restrict__ x,
                                                   float* __restrict__ x1) {
    const int colu = blockIdx.x * 256 + threadIdx.x;  // 0..4095
    const int s0 = blockIdx.y * SCAN_L;

    const u32* zp = (const u32*)z;
    const float2* xp = (const float2*)x;
    float2* x1p = (float2*)x1;

    float r0 = 0.f, r1 = 0.f;

    // ---- warm-up: runtime-bounded (nw in {0,64,128}), 4-deep prefetch ----
    {
        int sb = s0 - SCAN_H;
        if (sb < 0) sb = 0;
        const int nw = s0 - sb;
        if (nw > 0) {  // nw >= 64, multiple of 4
            u32 zq[4];
#pragma unroll
            for (int j = 0; j < 4; j++) zq[j] = zp[(long)(sb + j) * NCOLU + colu];
            for (int i = 0; i < nw; i += 4) {
#pragma unroll
                for (int j = 0; j < 4; j++) {
                    const u32 zz = zq[j];
                    if (i + j + 4 < nw)
                        zq[j] = zp[(long)(sb + i + j + 4) * NCOLU + colu];
                    r0 = ALPHA * (bf2f((u16)(zz & 0xffffu)) + r0);
                    r1 = ALPHA * (bf2f((u16)(zz >> 16)) + r1);
                }
            }
        }
    }

    float ap = powf(ALPHA, (float)(s0 + 2));  // alpha^{s0+2}

    // ---- main: 4-deep prefetch of z and x (fixed trip count) ----
    u32 zq[4];
    float2 xq[4];
#pragma unroll
    for (int j = 0; j < 4; j++) {
        zq[j] = zp[(long)(s0 + j) * NCOLU + colu];
        xq[j] = xp[(long)(s0 + j) * NCOLU + colu];
    }
#pragma unroll 4
    for (int i = 0; i < SCAN_L; i++) {
        const int sl = i & 3;  // compile-time per unrolled instance
        const u32 zz = zq[sl];
        const float2 xx = xq[sl];
        if (i + 4 < SCAN_L) {
            zq[sl] = zp[(long)(s0 + i + 4) * NCOLU + colu];
            xq[sl] = xp[(long)(s0 + i + 4) * NCOLU + colu];
        }
        const float z0 = bf2f((u16)(zz & 0xffffu));
        const float z1 = bf2f((u16)(zz >> 16));
        r0 = ALPHA * (z0 + r0);
        r1 = ALPHA * (z1 + r1);
        const float c = 1.f - (ALPHA - ap) * 10.f;  // 10 = 1/(1-alpha)
        ap *= ALPHA;
        x1p[(long)(s0 + i) * NCOLU + colu] = (float2){xx.x + r0 + c * z0, xx.y + r1 + c * z1};
    }
}

// ---------------------------------------------------------------------------
// GEMM 256x256 / BK=64 / 8 waves / fine-interleave 4-phase (r8 structure —
// session-best, FF2 103us).  ROUND-11 single change: swizzle uses ROW BIT 1
// (r5's measured-zero-conflict formula) instead of row bit 2 (r8 had 6.3M
// conflict cycles):
//   stage source octet c = (o&3) ^ ((o>>3)&3)   [= oct ^ ((row>>1)&3)]
//   read octet          = q16 ^ ((l15>>1)&3)
// Involution: fragment rows === l15 (mod 16) -> (row>>1)&3 = (l15>>1)&3.
//   C[M,N] = epi(A[M,K] @ Bt[N,K]^T + bias[N])
// - LDS [dbuf][k-half][256 rows][32 k] for A and B (128 KiB). Half-tile =
//   1024 octets = 2 gld_lds/thread; dest LINEAR (m104).
// - Per K-tile 4 phases: (k0,m-lo)(k0,m-hi)(k1,m-lo)(k1,m-hi); each phase:
//   ds_read frags -> stage ONE half-tile of t+1 -> 16 MFMA under setprio
//   -> [vmcnt(4) at phases 2,4 only] -> sched_barrier(0) -> s_barrier.
// - vmcnt ledger (issue order A(t,k0),B(t,k0),A(t,k1),B(t,k1)):
//   ph2-end outstanding = t.k1(4)+(t+1).k0(4) -> vmcnt(4) retires t.k1;
//   ph4-end retires (t+1).k0. Last tile vmcnt(0). In-order retirement.
// - XCD decode (verified r5): d=bx+by*gx; wgid=(d&7)*(nwg/8)+(d>>3);
//   m0=wgid/gy (n-fastest) -> A-panel fetched once per XCD, L2-shared.
// EPI: 0=+bias  1=relu(+bias)  2=+bias+resid(fp32);  OUT_F32 selects store type
// ---------------------------------------------------------------------------
#define BM 256
#define BN 256
#define BKK 64

typedef __attribute__((address_space(1))) unsigned int as1_u32;
typedef __attribute__((address_space(3))) unsigned int as3_u32;

__device__ __forceinline__ void gld_lds16(const void* g, const void* l) {
    __builtin_amdgcn_global_load_lds((as1_u32*)(unsigned long long)g,
                                     (as3_u32*)(unsigned int)(unsigned long long)l,
                                     16, 0, 0);
}

template <int EPI, bool OUT_F32>
__global__ __launch_bounds__(512, 2) void gemm8p(const u16* __restrict__ A,
                                                 const u16* __restrict__ Bt,
                                                 const float* __restrict__ bias,
                                                 const float* __restrict__ resid,
                                                 void* __restrict__ C,
                                                 int M, int N, int K) {
    __shared__ alignas(16) u16 sA[2][2][256 * 32];   // [dbuf][khalf][row*32k] 64 KiB
    __shared__ alignas(16) u16 sB[2][2][256 * 32];   // 64 KiB

    const int tid = threadIdx.x;
    const int lane = tid & 63;
    const int wave = tid >> 6;      // 8 waves: 2M x 4N, each owns 128x64
    const int wr = wave >> 2;       // 0..1
    const int wc = wave & 3;        // 0..3
    const int l15 = lane & 15, q16 = lane >> 4;

    // dispatch-anchored bijective XCD swizzle; n-fastest within an XCD chunk
    const int gy = gridDim.y;
    const int nwg = gridDim.x * gy;
    const int d = blockIdx.y * gridDim.x + blockIdx.x;  // HW dispatch order
    const int wgid = (d & 7) * (nwg >> 3) + (d >> 3);
    const int m0 = (wgid / gy) * BM;
    const int n0 = (wgid % gy) * BN;

    // ---- staging: half-tile = [256 rows][32 k] = 1024 octets; thread gets
    //      octets {tid, tid+512}. o -> row o>>2, dest slot o (linear),
    //      source octet-in-half c = (o&3) ^ ((o>>3)&3)  [r11: row bit 1] ----
    const u16* gA[2];
    const u16* gB[2];
    int dsto[2];
#pragma unroll
    for (int j = 0; j < 2; j++) {
        const int o = tid + j * 512;
        const int r = o >> 2;
        const int c = (o & 3) ^ ((o >> 3) & 3);
        gA[j] = A + (long)(m0 + r) * K + c * 8;   // + koff + kh*32 at stage time
        gB[j] = Bt + (long)(n0 + r) * K + c * 8;
        dsto[j] = o * 8;                           // u16 elems within khalf block
    }

    // ---- fragment read addressing (r5 zero-conflict formula) ----
    const int xoct = (q16 ^ ((l15 >> 1) & 3)) * 8;  // swizzled k-octet (elems)
    const int rowA = wr * 128 + l15;
    const int rowB = wc * 64 + l15;

    f32x4 acc[8][4];
#pragma unroll
    for (int i = 0; i < 8; i++)
#pragma unroll
        for (int j = 0; j < 4; j++) acc[i][j] = (f32x4){0.f, 0.f, 0.f, 0.f};

    const int NT = K / BKK;

// koff is an ELEMENT offset into the K dimension
#define STG_A(bs, kh, koff)                                                 \
    {                                                                       \
        gld_lds16(gA[0] + (koff) + (kh) * 32, &sA[bs][kh][dsto[0]]);        \
        gld_lds16(gA[1] + (koff) + (kh) * 32, &sA[bs][kh][dsto[1]]);        \
    }
#define STG_B(bs, kh, koff)                                                 \
    {                                                                       \
        gld_lds16(gB[0] + (koff) + (kh) * 32, &sB[bs][kh][dsto[0]]);        \
        gld_lds16(gB[1] + (koff) + (kh) * 32, &sB[bs][kh][dsto[1]]);        \
    }
#define MFMA16(mh)                                                          \
    {                                                                       \
        __builtin_amdgcn_s_setprio(1);                                      \
        _Pragma("unroll") for (int mi = 0; mi < 4; mi++)                    \
            _Pragma("unroll") for (int nj = 0; nj < 4; nj++)                \
                acc[(mh)*4 + mi][nj] = __builtin_amdgcn_mfma_f32_16x16x32_bf16( \
                    af[mi], bf[nj], acc[(mh)*4 + mi][nj], 0, 0, 0);         \
        __builtin_amdgcn_s_setprio(0);                                      \
    }
#define PHASE_END                                                           \
    {                                                                       \
        __builtin_amdgcn_sched_barrier(0);                                  \
        __builtin_amdgcn_s_barrier();                                       \
    }

    // prologue: stage tile 0's 4 half-tiles; wait until k0 pair landed
    STG_A(0, 0, 0); STG_B(0, 0, 0); STG_A(0, 1, 0); STG_B(0, 1, 0);
    asm volatile("s_waitcnt vmcnt(4)" ::: "memory");
    __builtin_amdgcn_s_barrier();

#pragma unroll 1
    for (int t = 0; t < NT; ++t) {
        const int b = t & 1, bn = b ^ 1;
        const int ko = (t + 1) * BKK;   // element offset of tile t+1
        const bool nx = (t + 1 < NT);
        short8 af[4], bf[4];

        // ---- phase 1: kk=0, m-lo ----
#pragma unroll
        for (int nj = 0; nj < 4; nj++)
            bf[nj] = *(const short8*)(&sB[b][0][(rowB + nj * 16) * 32 + xoct]);
#pragma unroll
        for (int mi = 0; mi < 4; mi++)
            af[mi] = *(const short8*)(&sA[b][0][(rowA + mi * 16) * 32 + xoct]);
        if (nx) STG_A(bn, 0, ko);
        MFMA16(0);
        PHASE_END;

        // ---- phase 2: kk=0, m-hi ----
#pragma unroll
        for (int mi = 0; mi < 4; mi++)
            af[mi] = *(const short8*)(&sA[b][0][(rowA + 64 + mi * 16) * 32 + xoct]);
        if (nx) STG_B(bn, 0, ko);
        MFMA16(1);
        if (nx) asm volatile("s_waitcnt vmcnt(4)" ::: "memory");  // t.k1 landed
        else    asm volatile("s_waitcnt vmcnt(0)" ::: "memory");
        PHASE_END;

        // ---- phase 3: kk=1, m-lo ----
#pragma unroll
        for (int nj = 0; nj < 4; nj++)
            bf[nj] = *(const short8*)(&sB[b][1][(rowB + nj * 16) * 32 + xoct]);
#pragma unroll
        for (int mi = 0; mi < 4; mi++)
            af[mi] = *(const short8*)(&sA[b][1][(rowA + mi * 16) * 32 + xoct]);
        if (nx) STG_A(bn, 1, ko);
        MFMA16(0);
        PHASE_END;

        // ---- phase 4: kk=1, m-hi ----
#pragma unroll
        for (int mi = 0; mi < 4; mi++)
            af[mi] = *(const short8*)(&sA[b][1][(rowA + 64 + mi * 16) * 32 + xoct]);
        if (nx) STG_B(bn, 1, ko);
        MFMA16(1);
        if (nx) asm volatile("s_waitcnt vmcnt(4)" ::: "memory");  // (t+1).k0 landed
        else    asm volatile("s_waitcnt vmcnt(0)" ::: "memory");
        PHASE_END;
    }

    // ---- epilogue: C/D layout col=lane&15, row=(lane>>4)*4+reg ----
#pragma unroll
    for (int mf = 0; mf < 8; mf++) {
        const int row0 = m0 + wr * 128 + mf * 16 + q16 * 4;
#pragma unroll
        for (int nj = 0; nj < 4; nj++) {
            const int col = n0 + wc * 64 + nj * 16 + l15;
            const float bv = bias[col];
#pragma unroll
            for (int r = 0; r < 4; r++) {
                const long idx = (long)(row0 + r) * N + col;
                float v = acc[mf][nj][r] + bv;
                if (EPI == 1) v = fmaxf(v, 0.f);
                if (EPI == 2) v += resid[idx];
                if (OUT_F32)
                    ((float*)C)[idx] = v;
                else
                    ((u16*)C)[idx] = f2bf(v);
            }
        }
    }
#undef STG_A
#undef STG_B
#undef MFMA16
#undef PHASE_END
}

// ---------------------------------------------------------------------------
extern "C" void kernel_launch(void* const* d_in, const int* in_sizes, int n_in,
                              void* d_out, int out_size, void* d_ws, size_t ws_size,
                              hipStream_t stream) {
    const float* x = (const float*)d_in[0];
    const float* w_lin = (const float*)d_in[1];
    const float* b_lin = (const float*)d_in[2];
    const float* w1 = (const float*)d_in[3];
    const float* b1 = (const float*)d_in[4];
    const float* w2 = (const float*)d_in[5];
    const float* b2 = (const float*)d_in[6];
    const float* g1 = (const float*)d_in[7];
    const float* be1 = (const float*)d_in[8];
    const float* g2 = (const float*)d_in[9];
    const float* be2 = (const float*)d_in[10];
    float* out = (float*)d_out;

    char* ws = (char*)d_ws;
    const size_t MB = 1024 * 1024;
    u16* y = (u16*)(ws);                       // LN output bf16, 32 MB
    float* x1 = (float*)(ws + 32 * MB);        // attn residual fp32, 64 MB
    u16* h = (u16*)(ws + 96 * MB);             // FF hidden bf16, 128 MB
    u16* z = h;                                // projection bf16, 32 MB (aliases h; z dies before h is written)
    u16* wb_lin = (u16*)(ws + 224 * MB);       // bf16 weights
    u16* wb1 = (u16*)(ws + 225 * MB);
    u16* wb2 = (u16*)(ws + 228 * MB);

    // 0) convert weights fp32 -> bf16
    cvt_kernel<<<(DMODEL * DMODEL) / 1024, 256, 0, stream>>>(w_lin, wb_lin, DMODEL * DMODEL);
    cvt_kernel<<<(FFDIM * DMODEL) / 1024, 256, 0, stream>>>(w1, wb1, FFDIM * DMODEL);
    cvt_kernel<<<(DMODEL * FFDIM) / 1024, 256, 0, stream>>>(w2, wb2, DMODEL * FFDIM);

    // 1) y = LN(x; g1, be1)
    ln_kernel<<<NTOK / 4, 256, 0, stream>>>(x, g1, be1, y);
    // 2) z = y @ w_lin^T + b_lin
    gemm8p<0, false><<<dim3(NTOK / BM, DMODEL / BN), 512, 0, stream>>>(y, wb_lin, b_lin, nullptr,
                                                                      z, NTOK, DMODEL, DMODEL);
    // 3) x1 = x + W @ z   (exp-decay scan)
    scan_kernel<<<dim3(NCOLU / 256, SEQ / SCAN_L), 256, 0, stream>>>(z, x, x1);
    // 4) y = LN(x1; g2, be2)
    ln_kernel<<<NTOK / 4, 256, 0, stream>>>(x1, g2, be2, y);
    // 5) h = relu(y @ w1^T + b1)
    gemm8p<1, false><<<dim3(NTOK / BM, FFDIM / BN), 512, 0, stream>>>(y, wb1, b1, nullptr, h,
                                                                     NTOK, FFDIM, DMODEL);
    // 6) out = x1 + h @ w2^T + b2
    gemm8p<2, true><<<dim3(NTOK / BM, DMODEL / BN), 512, 0, stream>>>(h, wb2, b2, x1, out,
                                                                     NTOK, DMODEL, FFDIM);
}

// Round 13
// 421.084 us; speedup vs baseline: 1.3470x; 1.0202x over previous
//
#include <hip/hip_runtime.h>

#define SEQ 2048
#define BATCH 16
#define DMODEL 512
#define FFDIM 2048
#define NTOK (SEQ * BATCH) /* 32768 tokens */
#define ALPHA 0.9f

typedef unsigned short u16;
typedef unsigned int u32;
typedef __attribute__((ext_vector_type(8))) short short8;
typedef __attribute__((ext_vector_type(4))) float f32x4;

__device__ __forceinline__ float bf2f(u16 u) {
    unsigned int v = ((unsigned int)u) << 16;
    return __builtin_bit_cast(float, v);
}
__device__ __forceinline__ u16 f2bf(float f) {
    unsigned int v = __builtin_bit_cast(unsigned int, f);
    v += 0x7fffu + ((v >> 16) & 1u);   // RNE
    return (u16)(v >> 16);
}

// ---------------------------------------------------------------------------
// fp32 -> bf16 conversion (weights), 4 elems/thread
// ---------------------------------------------------------------------------
__global__ __launch_bounds__(256) void cvt_kernel(const float* __restrict__ in,
                                                  u16* __restrict__ out, int n) {
    const int i = (blockIdx.x * 256 + threadIdx.x) * 4;
    if (i >= n) return;
    float4 v = *(const float4*)(in + i);
    ushort4 o;
    o.x = f2bf(v.x); o.y = f2bf(v.y); o.z = f2bf(v.z); o.w = f2bf(v.w);
    *(ushort4*)(out + i) = o;
}

// ---------------------------------------------------------------------------
// LayerNorm: one wave per token (64 lanes x 8 elems = 512 = DMODEL)
// ---------------------------------------------------------------------------
__global__ __launch_bounds__(256) void ln_kernel(const float* __restrict__ xin,
                                                 const float* __restrict__ g,
                                                 const float* __restrict__ b,
                                                 u16* __restrict__ y) {
    const int lane = threadIdx.x & 63;
    const int wave = threadIdx.x >> 6;
    const long tok = (long)blockIdx.x * 4 + wave;
    const long off = tok * DMODEL + lane * 8;

    float f[8];
    {
        const float4* xp = (const float4*)(xin + off);
        float4 a = xp[0], c = xp[1];
        f[0] = a.x; f[1] = a.y; f[2] = a.z; f[3] = a.w;
        f[4] = c.x; f[5] = c.y; f[6] = c.z; f[7] = c.w;
    }
    float s = 0.f, s2 = 0.f;
#pragma unroll
    for (int i = 0; i < 8; i++) { s += f[i]; s2 += f[i] * f[i]; }
#pragma unroll
    for (int o = 32; o > 0; o >>= 1) {
        s += __shfl_xor(s, o, 64);
        s2 += __shfl_xor(s2, o, 64);
    }
    const float mean = s * (1.f / DMODEL);
    const float var = s2 * (1.f / DMODEL) - mean * mean;
    const float inv = rsqrtf(var + 1e-5f);

    const float4* gp = (const float4*)(g + lane * 8);
    const float4* bp = (const float4*)(b + lane * 8);
    float4 g0 = gp[0], g1 = gp[1], b0 = bp[0], b1 = bp[1];
    float gg[8] = {g0.x, g0.y, g0.z, g0.w, g1.x, g1.y, g1.z, g1.w};
    float bb[8] = {b0.x, b0.y, b0.z, b0.w, b1.x, b1.y, b1.z, b1.w};
    short8 ov;
#pragma unroll
    for (int i = 0; i < 8; i++)
        ov[i] = (short)f2bf((f[i] - mean) * inv * gg[i] + bb[i]);
    *(short8*)(y + off) = ov;
}

// ---------------------------------------------------------------------------
// Carry-split exp-decay scan — removes warm-up entirely (exact).
//   r_s = alpha*(z_s + r_{s-1});  x1_s = x_s + r_s + c_s*z_s
// Chunked at L=64:  W_c = sum_j alpha^(64-j) z[c*64+j]   (kernel A, parallel)
//                   R_{c+1} = alpha^64 * R_c + W_c        (kernel B, tiny)
//                   main scan seeded with exact R_c        (kernel C)
// z traffic 96->64 MB, serial chain 192->64 iters, no truncation error.
// ---------------------------------------------------------------------------
#define SCAN_L 64
#define NCHUNK (SEQ / SCAN_L) /* 32 */
#define NCOLU (BATCH * DMODEL / 2) /* 4096 u32 columns, row stride 4096 */
#define A64 1.17901846e-3f /* 0.9^64 */

__global__ __launch_bounds__(256) void wsum_kernel(const u16* __restrict__ z,
                                                   float* __restrict__ W) {
    const int colu = blockIdx.x * 256 + threadIdx.x;  // 0..4095
    const int c = blockIdx.y;
    const int sb = c * SCAN_L;
    const u32* zp = (const u32*)z;

    float w0 = 0.f, w1 = 0.f;
    u32 zq[4];
#pragma unroll
    for (int j = 0; j < 4; j++) zq[j] = zp[(long)(sb + j) * NCOLU + colu];
#pragma unroll 4
    for (int i = 0; i < SCAN_L; i++) {
        const int sl = i & 3;
        const u32 zz = zq[sl];
        if (i + 4 < SCAN_L) zq[sl] = zp[(long)(sb + i + 4) * NCOLU + colu];
        w0 = ALPHA * (bf2f((u16)(zz & 0xffffu)) + w0);
        w1 = ALPHA * (bf2f((u16)(zz >> 16)) + w1);
    }
    ((float2*)W)[(long)c * NCOLU + colu] = (float2){w0, w1};
}

__global__ __launch_bounds__(256) void carry_kernel(const float* __restrict__ W,
                                                    float* __restrict__ R) {
    const int col = blockIdx.x * 256 + threadIdx.x;  // 0..8191
    float r = 0.f;
#pragma unroll
    for (int c = 0; c < NCHUNK; c++) {
        R[(long)c * 8192 + col] = r;           // carry INTO chunk c = r_{c*64-1}
        r = A64 * r + W[(long)c * 8192 + col];
    }
}

__global__ __launch_bounds__(256) void scan_kernel(const u16* __restrict__ z,
                                                   const float* __restrict__ x,
                                                   const float* __restrict__ Rbuf,
                                                   float* __restrict__ x1) {
    const int colu = blockIdx.x * 256 + threadIdx.x;  // 0..4095
    const int c = blockIdx.y;
    const int s0 = c * SCAN_L;

    const u32* zp = (const u32*)z;
    const float2* xp = (const float2*)x;
    float2* x1p = (float2*)x1;

    const float2 rr = ((const float2*)Rbuf)[(long)c * NCOLU + colu];
    float r0 = rr.x, r1 = rr.y;

    float ap = powf(ALPHA, (float)(s0 + 2));  // alpha^{s0+2}

    u32 zq[4];
    float2 xq[4];
#pragma unroll
    for (int j = 0; j < 4; j++) {
        zq[j] = zp[(long)(s0 + j) * NCOLU + colu];
        xq[j] = xp[(long)(s0 + j) * NCOLU + colu];
    }
#pragma unroll 4
    for (int i = 0; i < SCAN_L; i++) {
        const int sl = i & 3;  // compile-time per unrolled instance
        const u32 zz = zq[sl];
        const float2 xx = xq[sl];
        if (i + 4 < SCAN_L) {
            zq[sl] = zp[(long)(s0 + i + 4) * NCOLU + colu];
            xq[sl] = xp[(long)(s0 + i + 4) * NCOLU + colu];
        }
        const float z0 = bf2f((u16)(zz & 0xffffu));
        const float z1 = bf2f((u16)(zz >> 16));
        r0 = ALPHA * (z0 + r0);
        r1 = ALPHA * (z1 + r1);
        const float cc = 1.f - (ALPHA - ap) * 10.f;  // 10 = 1/(1-alpha)
        ap *= ALPHA;
        x1p[(long)(s0 + i) * NCOLU + colu] = (float2){xx.x + r0 + cc * z0, xx.y + r1 + cc * z1};
    }
}

// ---------------------------------------------------------------------------
// GEMM 256x256 / BK=64 / 8 waves / fine-interleave 4-phase (r11 — session
// best, verbatim).  Swizzle: row bit 1 (measured 0 bank conflicts).
//   stage source octet c = (o&3) ^ ((o>>3)&3); read octet q16 ^ ((l15>>1)&3).
//   C[M,N] = epi(A[M,K] @ Bt[N,K]^T + bias[N])
// vmcnt ledger (issue order A(t,k0),B(t,k0),A(t,k1),B(t,k1)):
//   ph2-end outstanding = t.k1(4)+(t+1).k0(4) -> vmcnt(4) retires t.k1;
//   ph4-end retires (t+1).k0. Last tile vmcnt(0). In-order retirement.
// XCD decode: d=bx+by*gx; wgid=(d&7)*(nwg/8)+(d>>3); m0=wgid/gy (n-fastest).
// EPI: 0=+bias  1=relu(+bias)  2=+bias+resid(fp32);  OUT_F32 selects store type
// ---------------------------------------------------------------------------
#define BM 256
#define BN 256
#define BKK 64

typedef __attribute__((address_space(1))) unsigned int as1_u32;
typedef __attribute__((address_space(3))) unsigned int as3_u32;

__device__ __forceinline__ void gld_lds16(const void* g, const void* l) {
    __builtin_amdgcn_global_load_lds((as1_u32*)(unsigned long long)g,
                                     (as3_u32*)(unsigned int)(unsigned long long)l,
                                     16, 0, 0);
}

template <int EPI, bool OUT_F32>
__global__ __launch_bounds__(512, 2) void gemm8p(const u16* __restrict__ A,
                                                 const u16* __restrict__ Bt,
                                                 const float* __restrict__ bias,
                                                 const float* __restrict__ resid,
                                                 void* __restrict__ C,
                                                 int M, int N, int K) {
    __shared__ alignas(16) u16 sA[2][2][256 * 32];   // [dbuf][khalf][row*32k] 64 KiB
    __shared__ alignas(16) u16 sB[2][2][256 * 32];   // 64 KiB

    const int tid = threadIdx.x;
    const int lane = tid & 63;
    const int wave = tid >> 6;      // 8 waves: 2M x 4N, each owns 128x64
    const int wr = wave >> 2;       // 0..1
    const int wc = wave & 3;        // 0..3
    const int l15 = lane & 15, q16 = lane >> 4;

    // dispatch-anchored bijective XCD swizzle; n-fastest within an XCD chunk
    const int gy = gridDim.y;
    const int nwg = gridDim.x * gy;
    const int d = blockIdx.y * gridDim.x + blockIdx.x;  // HW dispatch order
    const int wgid = (d & 7) * (nwg >> 3) + (d >> 3);
    const int m0 = (wgid / gy) * BM;
    const int n0 = (wgid % gy) * BN;

    // ---- staging: half-tile = [256 rows][32 k] = 1024 octets; thread gets
    //      octets {tid, tid+512}. o -> row o>>2, dest slot o (linear),
    //      source octet-in-half c = (o&3) ^ ((o>>3)&3)  [row bit 1] ----
    const u16* gA[2];
    const u16* gB[2];
    int dsto[2];
#pragma unroll
    for (int j = 0; j < 2; j++) {
        const int o = tid + j * 512;
        const int r = o >> 2;
        const int c = (o & 3) ^ ((o >> 3) & 3);
        gA[j] = A + (long)(m0 + r) * K + c * 8;   // + koff + kh*32 at stage time
        gB[j] = Bt + (long)(n0 + r) * K + c * 8;
        dsto[j] = o * 8;                           // u16 elems within khalf block
    }

    // ---- fragment read addressing (zero-conflict formula) ----
    const int xoct = (q16 ^ ((l15 >> 1) & 3)) * 8;  // swizzled k-octet (elems)
    const int rowA = wr * 128 + l15;
    const int rowB = wc * 64 + l15;

    f32x4 acc[8][4];
#pragma unroll
    for (int i = 0; i < 8; i++)
#pragma unroll
        for (int j = 0; j < 4; j++) acc[i][j] = (f32x4){0.f, 0.f, 0.f, 0.f};

    const int NT = K / BKK;

// koff is an ELEMENT offset into the K dimension
#define STG_A(bs, kh, koff)                                                 \
    {                                                                       \
        gld_lds16(gA[0] + (koff) + (kh) * 32, &sA[bs][kh][dsto[0]]);        \
        gld_lds16(gA[1] + (koff) + (kh) * 32, &sA[bs][kh][dsto[1]]);        \
    }
#define STG_B(bs, kh, koff)                                                 \
    {                                                                       \
        gld_lds16(gB[0] + (koff) + (kh) * 32, &sB[bs][kh][dsto[0]]);        \
        gld_lds16(gB[1] + (koff) + (kh) * 32, &sB[bs][kh][dsto[1]]);        \
    }
#define MFMA16(mh)                                                          \
    {                                                                       \
        __builtin_amdgcn_s_setprio(1);                                      \
        _Pragma("unroll") for (int mi = 0; mi < 4; mi++)                    \
            _Pragma("unroll") for (int nj = 0; nj < 4; nj++)                \
                acc[(mh)*4 + mi][nj] = __builtin_amdgcn_mfma_f32_16x16x32_bf16( \
                    af[mi], bf[nj], acc[(mh)*4 + mi][nj], 0, 0, 0);         \
        __builtin_amdgcn_s_setprio(0);                                      \
    }
#define PHASE_END                                                           \
    {                                                                       \
        __builtin_amdgcn_sched_barrier(0);                                  \
        __builtin_amdgcn_s_barrier();                                       \
    }

    // prologue: stage tile 0's 4 half-tiles; wait until k0 pair landed
    STG_A(0, 0, 0); STG_B(0, 0, 0); STG_A(0, 1, 0); STG_B(0, 1, 0);
    asm volatile("s_waitcnt vmcnt(4)" ::: "memory");
    __builtin_amdgcn_s_barrier();

#pragma unroll 1
    for (int t = 0; t < NT; ++t) {
        const int b = t & 1, bn = b ^ 1;
        const int ko = (t + 1) * BKK;   // element offset of tile t+1
        const bool nx = (t + 1 < NT);
        short8 af[4], bf[4];

        // ---- phase 1: kk=0, m-lo ----
#pragma unroll
        for (int nj = 0; nj < 4; nj++)
            bf[nj] = *(const short8*)(&sB[b][0][(rowB + nj * 16) * 32 + xoct]);
#pragma unroll
        for (int mi = 0; mi < 4; mi++)
            af[mi] = *(const short8*)(&sA[b][0][(rowA + mi * 16) * 32 + xoct]);
        if (nx) STG_A(bn, 0, ko);
        MFMA16(0);
        PHASE_END;

        // ---- phase 2: kk=0, m-hi ----
#pragma unroll
        for (int mi = 0; mi < 4; mi++)
            af[mi] = *(const short8*)(&sA[b][0][(rowA + 64 + mi * 16) * 32 + xoct]);
        if (nx) STG_B(bn, 0, ko);
        MFMA16(1);
        if (nx) asm volatile("s_waitcnt vmcnt(4)" ::: "memory");  // t.k1 landed
        else    asm volatile("s_waitcnt vmcnt(0)" ::: "memory");
        PHASE_END;

        // ---- phase 3: kk=1, m-lo ----
#pragma unroll
        for (int nj = 0; nj < 4; nj++)
            bf[nj] = *(const short8*)(&sB[b][1][(rowB + nj * 16) * 32 + xoct]);
#pragma unroll
        for (int mi = 0; mi < 4; mi++)
            af[mi] = *(const short8*)(&sA[b][1][(rowA + mi * 16) * 32 + xoct]);
        if (nx) STG_A(bn, 1, ko);
        MFMA16(0);
        PHASE_END;

        // ---- phase 4: kk=1, m-hi ----
#pragma unroll
        for (int mi = 0; mi < 4; mi++)
            af[mi] = *(const short8*)(&sA[b][1][(rowA + 64 + mi * 16) * 32 + xoct]);
        if (nx) STG_B(bn, 1, ko);
        MFMA16(1);
        if (nx) asm volatile("s_waitcnt vmcnt(4)" ::: "memory");  // (t+1).k0 landed
        else    asm volatile("s_waitcnt vmcnt(0)" ::: "memory");
        PHASE_END;
    }

    // ---- epilogue: C/D layout col=lane&15, row=(lane>>4)*4+reg ----
#pragma unroll
    for (int mf = 0; mf < 8; mf++) {
        const int row0 = m0 + wr * 128 + mf * 16 + q16 * 4;
#pragma unroll
        for (int nj = 0; nj < 4; nj++) {
            const int col = n0 + wc * 64 + nj * 16 + l15;
            const float bv = bias[col];
#pragma unroll
            for (int r = 0; r < 4; r++) {
                const long idx = (long)(row0 + r) * N + col;
                float v = acc[mf][nj][r] + bv;
                if (EPI == 1) v = fmaxf(v, 0.f);
                if (EPI == 2) v += resid[idx];
                if (OUT_F32)
                    ((float*)C)[idx] = v;
                else
                    ((u16*)C)[idx] = f2bf(v);
            }
        }
    }
#undef STG_A
#undef STG_B
#undef MFMA16
#undef PHASE_END
}

// ---------------------------------------------------------------------------
extern "C" void kernel_launch(void* const* d_in, const int* in_sizes, int n_in,
                              void* d_out, int out_size, void* d_ws, size_t ws_size,
                              hipStream_t stream) {
    const float* x = (const float*)d_in[0];
    const float* w_lin = (const float*)d_in[1];
    const float* b_lin = (const float*)d_in[2];
    const float* w1 = (const float*)d_in[3];
    const float* b1 = (const float*)d_in[4];
    const float* w2 = (const float*)d_in[5];
    const float* b2 = (const float*)d_in[6];
    const float* g1 = (const float*)d_in[7];
    const float* be1 = (const float*)d_in[8];
    const float* g2 = (const float*)d_in[9];
    const float* be2 = (const float*)d_in[10];
    float* out = (float*)d_out;

    char* ws = (char*)d_ws;
    const size_t MB = 1024 * 1024;
    u16* y = (u16*)(ws);                       // LN output bf16, 32 MB
    float* x1 = (float*)(ws + 32 * MB);        // attn residual fp32, 64 MB
    u16* h = (u16*)(ws + 96 * MB);             // FF hidden bf16, 128 MB (96..224)
    u16* z = h;                                // projection bf16, 32 MB (96..128; dies before h written)
    // scan scratch lives in the h region beyond z (dead until FF1 writes h in step 5):
    float* Wbuf = (float*)(ws + 160 * MB);     // chunk weighted sums, 1 MB
    float* Rbuf = (float*)(ws + 162 * MB);     // chunk carries, 1 MB
    u16* wb_lin = (u16*)(ws + 224 * MB);       // bf16 weights
    u16* wb1 = (u16*)(ws + 225 * MB);
    u16* wb2 = (u16*)(ws + 228 * MB);

    // 0) convert weights fp32 -> bf16
    cvt_kernel<<<(DMODEL * DMODEL) / 1024, 256, 0, stream>>>(w_lin, wb_lin, DMODEL * DMODEL);
    cvt_kernel<<<(FFDIM * DMODEL) / 1024, 256, 0, stream>>>(w1, wb1, FFDIM * DMODEL);
    cvt_kernel<<<(DMODEL * FFDIM) / 1024, 256, 0, stream>>>(w2, wb2, DMODEL * FFDIM);

    // 1) y = LN(x; g1, be1)
    ln_kernel<<<NTOK / 4, 256, 0, stream>>>(x, g1, be1, y);
    // 2) z = y @ w_lin^T + b_lin
    gemm8p<0, false><<<dim3(NTOK / BM, DMODEL / BN), 512, 0, stream>>>(y, wb_lin, b_lin, nullptr,
                                                                      z, NTOK, DMODEL, DMODEL);
    // 3) x1 = x + W @ z   (carry-split exp-decay scan, exact)
    wsum_kernel<<<dim3(NCOLU / 256, NCHUNK), 256, 0, stream>>>(z, Wbuf);
    carry_kernel<<<8192 / 256, 256, 0, stream>>>(Wbuf, Rbuf);
    scan_kernel<<<dim3(NCOLU / 256, NCHUNK), 256, 0, stream>>>(z, x, Rbuf, x1);
    // 4) y = LN(x1; g2, be2)
    ln_kernel<<<NTOK / 4, 256, 0, stream>>>(x1, g2, be2, y);
    // 5) h = relu(y @ w1^T + b1)
    gemm8p<1, false><<<dim3(NTOK / BM, FFDIM / BN), 512, 0, stream>>>(y, wb1, b1, nullptr, h,
                                                                     NTOK, FFDIM, DMODEL);
    // 6) out = x1 + h @ w2^T + b2
    gemm8p<2, true><<<dim3(NTOK / BM, DMODEL / BN), 512, 0, stream>>>(h, wb2, b2, x1, out,
                                                                     NTOK, DMODEL, FFDIM);
}

// Round 14
// 416.697 us; speedup vs baseline: 1.3612x; 1.0105x over previous
//
#include <hip/hip_runtime.h>

#define SEQ 2048
#define BATCH 16
#define DMODEL 512
#define FFDIM 2048
#define NTOK (SEQ * BATCH) /* 32768 tokens */
#define ALPHA 0.9f

typedef unsigned short u16;
typedef unsigned int u32;
typedef __attribute__((ext_vector_type(8))) short short8;
typedef __attribute__((ext_vector_type(4))) float f32x4;

__device__ __forceinline__ float bf2f(u16 u) {
    unsigned int v = ((unsigned int)u) << 16;
    return __builtin_bit_cast(float, v);
}
__device__ __forceinline__ u16 f2bf(float f) {
    unsigned int v = __builtin_bit_cast(unsigned int, f);
    v += 0x7fffu + ((v >> 16) & 1u);   // RNE
    return (u16)(v >> 16);
}

// ---------------------------------------------------------------------------
// fp32 -> bf16 conversion (weights), 4 elems/thread
// ---------------------------------------------------------------------------
__global__ __launch_bounds__(256) void cvt_kernel(const float* __restrict__ in,
                                                  u16* __restrict__ out, int n) {
    const int i = (blockIdx.x * 256 + threadIdx.x) * 4;
    if (i >= n) return;
    float4 v = *(const float4*)(in + i);
    ushort4 o;
    o.x = f2bf(v.x); o.y = f2bf(v.y); o.z = f2bf(v.z); o.w = f2bf(v.w);
    *(ushort4*)(out + i) = o;
}

// ---------------------------------------------------------------------------
// LayerNorm: one wave per token (64 lanes x 8 elems = 512 = DMODEL)
// ---------------------------------------------------------------------------
__global__ __launch_bounds__(256) void ln_kernel(const float* __restrict__ xin,
                                                 const float* __restrict__ g,
                                                 const float* __restrict__ b,
                                                 u16* __restrict__ y) {
    const int lane = threadIdx.x & 63;
    const int wave = threadIdx.x >> 6;
    const long tok = (long)blockIdx.x * 4 + wave;
    const long off = tok * DMODEL + lane * 8;

    float f[8];
    {
        const float4* xp = (const float4*)(xin + off);
        float4 a = xp[0], c = xp[1];
        f[0] = a.x; f[1] = a.y; f[2] = a.z; f[3] = a.w;
        f[4] = c.x; f[5] = c.y; f[6] = c.z; f[7] = c.w;
    }
    float s = 0.f, s2 = 0.f;
#pragma unroll
    for (int i = 0; i < 8; i++) { s += f[i]; s2 += f[i] * f[i]; }
#pragma unroll
    for (int o = 32; o > 0; o >>= 1) {
        s += __shfl_xor(s, o, 64);
        s2 += __shfl_xor(s2, o, 64);
    }
    const float mean = s * (1.f / DMODEL);
    const float var = s2 * (1.f / DMODEL) - mean * mean;
    const float inv = rsqrtf(var + 1e-5f);

    const float4* gp = (const float4*)(g + lane * 8);
    const float4* bp = (const float4*)(b + lane * 8);
    float4 g0 = gp[0], g1 = gp[1], b0 = bp[0], b1 = bp[1];
    float gg[8] = {g0.x, g0.y, g0.z, g0.w, g1.x, g1.y, g1.z, g1.w};
    float bb[8] = {b0.x, b0.y, b0.z, b0.w, b1.x, b1.y, b1.z, b1.w};
    short8 ov;
#pragma unroll
    for (int i = 0; i < 8; i++)
        ov[i] = (short)f2bf((f[i] - mean) * inv * gg[i] + bb[i]);
    *(short8*)(y + off) = ov;
}

// ---------------------------------------------------------------------------
// Carry-split exp-decay scan (verified r13) — no warm-up, exact.
//   r_s = alpha*(z_s + r_{s-1});  x1_s = x_s + r_s + c_s*z_s
// W_c = sum_j alpha^(64-j) z[c*64+j]  (wsum); R_{c+1}=alpha^64*R_c+W_c (carry);
// main scan seeded with exact R_c.
// ---------------------------------------------------------------------------
#define SCAN_L 64
#define NCHUNK (SEQ / SCAN_L) /* 32 */
#define NCOLU (BATCH * DMODEL / 2) /* 4096 u32 columns, row stride 4096 */
#define A64 1.17901846e-3f /* 0.9^64 */

__global__ __launch_bounds__(256) void wsum_kernel(const u16* __restrict__ z,
                                                   float* __restrict__ W) {
    const int colu = blockIdx.x * 256 + threadIdx.x;  // 0..4095
    const int c = blockIdx.y;
    const int sb = c * SCAN_L;
    const u32* zp = (const u32*)z;

    float w0 = 0.f, w1 = 0.f;
    u32 zq[4];
#pragma unroll
    for (int j = 0; j < 4; j++) zq[j] = zp[(long)(sb + j) * NCOLU + colu];
#pragma unroll 4
    for (int i = 0; i < SCAN_L; i++) {
        const int sl = i & 3;
        const u32 zz = zq[sl];
        if (i + 4 < SCAN_L) zq[sl] = zp[(long)(sb + i + 4) * NCOLU + colu];
        w0 = ALPHA * (bf2f((u16)(zz & 0xffffu)) + w0);
        w1 = ALPHA * (bf2f((u16)(zz >> 16)) + w1);
    }
    ((float2*)W)[(long)c * NCOLU + colu] = (float2){w0, w1};
}

__global__ __launch_bounds__(256) void carry_kernel(const float* __restrict__ W,
                                                    float* __restrict__ R) {
    const int col = blockIdx.x * 256 + threadIdx.x;  // 0..8191
    float r = 0.f;
#pragma unroll
    for (int c = 0; c < NCHUNK; c++) {
        R[(long)c * 8192 + col] = r;           // carry INTO chunk c = r_{c*64-1}
        r = A64 * r + W[(long)c * 8192 + col];
    }
}

__global__ __launch_bounds__(256) void scan_kernel(const u16* __restrict__ z,
                                                   const float* __restrict__ x,
                                                   const float* __restrict__ Rbuf,
                                                   float* __restrict__ x1) {
    const int colu = blockIdx.x * 256 + threadIdx.x;  // 0..4095
    const int c = blockIdx.y;
    const int s0 = c * SCAN_L;

    const u32* zp = (const u32*)z;
    const float2* xp = (const float2*)x;
    float2* x1p = (float2*)x1;

    const float2 rr = ((const float2*)Rbuf)[(long)c * NCOLU + colu];
    float r0 = rr.x, r1 = rr.y;

    float ap = powf(ALPHA, (float)(s0 + 2));  // alpha^{s0+2}

    u32 zq[4];
    float2 xq[4];
#pragma unroll
    for (int j = 0; j < 4; j++) {
        zq[j] = zp[(long)(s0 + j) * NCOLU + colu];
        xq[j] = xp[(long)(s0 + j) * NCOLU + colu];
    }
#pragma unroll 4
    for (int i = 0; i < SCAN_L; i++) {
        const int sl = i & 3;  // compile-time per unrolled instance
        const u32 zz = zq[sl];
        const float2 xx = xq[sl];
        if (i + 4 < SCAN_L) {
            zq[sl] = zp[(long)(s0 + i + 4) * NCOLU + colu];
            xq[sl] = xp[(long)(s0 + i + 4) * NCOLU + colu];
        }
        const float z0 = bf2f((u16)(zz & 0xffffu));
        const float z1 = bf2f((u16)(zz >> 16));
        r0 = ALPHA * (z0 + r0);
        r1 = ALPHA * (z1 + r1);
        const float cc = 1.f - (ALPHA - ap) * 10.f;  // 10 = 1/(1-alpha)
        ap *= ALPHA;
        x1p[(long)(s0 + i) * NCOLU + colu] = (float2){xx.x + r0 + cc * z0, xx.y + r1 + cc * z1};
    }
}

// ---------------------------------------------------------------------------
// GEMM 256x256 / BK=64 / 8 waves / m201-template phase schedule (round 14).
//   C[M,N] = epi(A[M,K] @ Bt[N,K]^T + bias[N])
// r11/r13 base (zero-conflict swizzle, counted vmcnt ledger, XCD decode)
// with the phase re-shaped to the m201 reference:
//   { ds_read frags ; stage 1 half-tile ; s_barrier ; lgkmcnt(0)+sched_barrier
//     ; setprio(1) 16xMFMA setprio(0) ; [vmcnt(4) at ph2/ph4] ; s_barrier }
// Mid-phase barrier: all waves enqueue ds_reads+staging BEFORE the barrier so
// LDS latency drains under wave-stagger; MFMA cluster opens with data ready.
// (m201 measures 62% MfmaUtil at this exact tile/wave/LDS geometry.)
// vmcnt ledger (issue order A(t,k0),B(t,k0),A(t,k1),B(t,k1)):
//   ph2 outstanding = t.k1(4)+(t+1).k0(4) -> vmcnt(4) retires t.k1 (guards
//   ph3 reads, which are after ph2's tail barrier). ph4 retires (t+1).k0
//   (guards next ph1). Last tile: vmcnt(0). In-order retirement.
// WAR: buffer sX[b][kh] last read at phase head; drained by that phase's
// lgkmcnt(0); overwritten >=2 barriers later. Safe.
// Swizzle (0 conflicts, measured): stage source octet c=(o&3)^((o>>3)&3);
// read octet q16^((l15>>1)&3); frag rows === l15 (mod 16) -> involution.
// XCD decode: d=bx+by*gx; wgid=(d&7)*(nwg/8)+(d>>3); m0=wgid/gy (n-fastest).
// EPI: 0=+bias  1=relu(+bias)  2=+bias+resid(fp32);  OUT_F32 selects store type
// ---------------------------------------------------------------------------
#define BM 256
#define BN 256
#define BKK 64

typedef __attribute__((address_space(1))) unsigned int as1_u32;
typedef __attribute__((address_space(3))) unsigned int as3_u32;

__device__ __forceinline__ void gld_lds16(const void* g, const void* l) {
    __builtin_amdgcn_global_load_lds((as1_u32*)(unsigned long long)g,
                                     (as3_u32*)(unsigned int)(unsigned long long)l,
                                     16, 0, 0);
}

template <int EPI, bool OUT_F32>
__global__ __launch_bounds__(512, 2) void gemm8p(const u16* __restrict__ A,
                                                 const u16* __restrict__ Bt,
                                                 const float* __restrict__ bias,
                                                 const float* __restrict__ resid,
                                                 void* __restrict__ C,
                                                 int M, int N, int K) {
    __shared__ alignas(16) u16 sA[2][2][256 * 32];   // [dbuf][khalf][row*32k] 64 KiB
    __shared__ alignas(16) u16 sB[2][2][256 * 32];   // 64 KiB

    const int tid = threadIdx.x;
    const int lane = tid & 63;
    const int wave = tid >> 6;      // 8 waves: 2M x 4N, each owns 128x64
    const int wr = wave >> 2;       // 0..1
    const int wc = wave & 3;        // 0..3
    const int l15 = lane & 15, q16 = lane >> 4;

    // dispatch-anchored bijective XCD swizzle; n-fastest within an XCD chunk
    const int gy = gridDim.y;
    const int nwg = gridDim.x * gy;
    const int d = blockIdx.y * gridDim.x + blockIdx.x;  // HW dispatch order
    const int wgid = (d & 7) * (nwg >> 3) + (d >> 3);
    const int m0 = (wgid / gy) * BM;
    const int n0 = (wgid % gy) * BN;

    // ---- staging: half-tile = [256 rows][32 k] = 1024 octets; thread gets
    //      octets {tid, tid+512}. o -> row o>>2, dest slot o (linear),
    //      source octet-in-half c = (o&3) ^ ((o>>3)&3)  [row bit 1] ----
    const u16* gA[2];
    const u16* gB[2];
    int dsto[2];
#pragma unroll
    for (int j = 0; j < 2; j++) {
        const int o = tid + j * 512;
        const int r = o >> 2;
        const int c = (o & 3) ^ ((o >> 3) & 3);
        gA[j] = A + (long)(m0 + r) * K + c * 8;   // + koff + kh*32 at stage time
        gB[j] = Bt + (long)(n0 + r) * K + c * 8;
        dsto[j] = o * 8;                           // u16 elems within khalf block
    }

    // ---- fragment read addressing (zero-conflict formula) ----
    const int xoct = (q16 ^ ((l15 >> 1) & 3)) * 8;  // swizzled k-octet (elems)
    const int rowA = wr * 128 + l15;
    const int rowB = wc * 64 + l15;

    f32x4 acc[8][4];
#pragma unroll
    for (int i = 0; i < 8; i++)
#pragma unroll
        for (int j = 0; j < 4; j++) acc[i][j] = (f32x4){0.f, 0.f, 0.f, 0.f};

    const int NT = K / BKK;

// koff is an ELEMENT offset into the K dimension
#define STG_A(bs, kh, koff)                                                 \
    {                                                                       \
        gld_lds16(gA[0] + (koff) + (kh) * 32, &sA[bs][kh][dsto[0]]);        \
        gld_lds16(gA[1] + (koff) + (kh) * 32, &sA[bs][kh][dsto[1]]);        \
    }
#define STG_B(bs, kh, koff)                                                 \
    {                                                                       \
        gld_lds16(gB[0] + (koff) + (kh) * 32, &sB[bs][kh][dsto[0]]);        \
        gld_lds16(gB[1] + (koff) + (kh) * 32, &sB[bs][kh][dsto[1]]);        \
    }
// m201 phase core: mid barrier between read-issue and MFMA cluster
#define PHASE_MID                                                           \
    {                                                                       \
        __builtin_amdgcn_s_barrier();                                       \
        asm volatile("s_waitcnt lgkmcnt(0)" ::: "memory");                  \
        __builtin_amdgcn_sched_barrier(0);                                  \
    }
#define MFMA16(mh)                                                          \
    {                                                                       \
        __builtin_amdgcn_s_setprio(1);                                      \
        _Pragma("unroll") for (int mi = 0; mi < 4; mi++)                    \
            _Pragma("unroll") for (int nj = 0; nj < 4; nj++)                \
                acc[(mh)*4 + mi][nj] = __builtin_amdgcn_mfma_f32_16x16x32_bf16( \
                    af[mi], bf[nj], acc[(mh)*4 + mi][nj], 0, 0, 0);         \
        __builtin_amdgcn_s_setprio(0);                                      \
    }
#define PHASE_TAIL                                                          \
    {                                                                       \
        __builtin_amdgcn_s_barrier();                                       \
    }

    // prologue: stage tile 0's 4 half-tiles; wait until k0 pair landed
    STG_A(0, 0, 0); STG_B(0, 0, 0); STG_A(0, 1, 0); STG_B(0, 1, 0);
    asm volatile("s_waitcnt vmcnt(4)" ::: "memory");
    __builtin_amdgcn_s_barrier();

#pragma unroll 1
    for (int t = 0; t < NT; ++t) {
        const int b = t & 1, bn = b ^ 1;
        const int ko = (t + 1) * BKK;   // element offset of tile t+1
        const bool nx = (t + 1 < NT);
        short8 af[4], bf[4];

        // ---- phase 1: kk=0, m-lo ----
#pragma unroll
        for (int nj = 0; nj < 4; nj++)
            bf[nj] = *(const short8*)(&sB[b][0][(rowB + nj * 16) * 32 + xoct]);
#pragma unroll
        for (int mi = 0; mi < 4; mi++)
            af[mi] = *(const short8*)(&sA[b][0][(rowA + mi * 16) * 32 + xoct]);
        if (nx) STG_A(bn, 0, ko);
        PHASE_MID;
        MFMA16(0);
        PHASE_TAIL;

        // ---- phase 2: kk=0, m-hi (bf persists from phase 1) ----
#pragma unroll
        for (int mi = 0; mi < 4; mi++)
            af[mi] = *(const short8*)(&sA[b][0][(rowA + 64 + mi * 16) * 32 + xoct]);
        if (nx) STG_B(bn, 0, ko);
        PHASE_MID;
        MFMA16(1);
        if (nx) asm volatile("s_waitcnt vmcnt(4)" ::: "memory");  // t.k1 landed
        else    asm volatile("s_waitcnt vmcnt(0)" ::: "memory");
        PHASE_TAIL;

        // ---- phase 3: kk=1, m-lo ----
#pragma unroll
        for (int nj = 0; nj < 4; nj++)
            bf[nj] = *(const short8*)(&sB[b][1][(rowB + nj * 16) * 32 + xoct]);
#pragma unroll
        for (int mi = 0; mi < 4; mi++)
            af[mi] = *(const short8*)(&sA[b][1][(rowA + mi * 16) * 32 + xoct]);
        if (nx) STG_A(bn, 1, ko);
        PHASE_MID;
        MFMA16(0);
        PHASE_TAIL;

        // ---- phase 4: kk=1, m-hi ----
#pragma unroll
        for (int mi = 0; mi < 4; mi++)
            af[mi] = *(const short8*)(&sA[b][1][(rowA + 64 + mi * 16) * 32 + xoct]);
        if (nx) STG_B(bn, 1, ko);
        PHASE_MID;
        MFMA16(1);
        if (nx) asm volatile("s_waitcnt vmcnt(4)" ::: "memory");  // (t+1).k0 landed
        else    asm volatile("s_waitcnt vmcnt(0)" ::: "memory");
        PHASE_TAIL;
    }

    // ---- epilogue: C/D layout col=lane&15, row=(lane>>4)*4+reg ----
#pragma unroll
    for (int mf = 0; mf < 8; mf++) {
        const int row0 = m0 + wr * 128 + mf * 16 + q16 * 4;
#pragma unroll
        for (int nj = 0; nj < 4; nj++) {
            const int col = n0 + wc * 64 + nj * 16 + l15;
            const float bv = bias[col];
#pragma unroll
            for (int r = 0; r < 4; r++) {
                const long idx = (long)(row0 + r) * N + col;
                float v = acc[mf][nj][r] + bv;
                if (EPI == 1) v = fmaxf(v, 0.f);
                if (EPI == 2) v += resid[idx];
                if (OUT_F32)
                    ((float*)C)[idx] = v;
                else
                    ((u16*)C)[idx] = f2bf(v);
            }
        }
    }
#undef STG_A
#undef STG_B
#undef PHASE_MID
#undef MFMA16
#undef PHASE_TAIL
}

// ---------------------------------------------------------------------------
extern "C" void kernel_launch(void* const* d_in, const int* in_sizes, int n_in,
                              void* d_out, int out_size, void* d_ws, size_t ws_size,
                              hipStream_t stream) {
    const float* x = (const float*)d_in[0];
    const float* w_lin = (const float*)d_in[1];
    const float* b_lin = (const float*)d_in[2];
    const float* w1 = (const float*)d_in[3];
    const float* b1 = (const float*)d_in[4];
    const float* w2 = (const float*)d_in[5];
    const float* b2 = (const float*)d_in[6];
    const float* g1 = (const float*)d_in[7];
    const float* be1 = (const float*)d_in[8];
    const float* g2 = (const float*)d_in[9];
    const float* be2 = (const float*)d_in[10];
    float* out = (float*)d_out;

    char* ws = (char*)d_ws;
    const size_t MB = 1024 * 1024;
    u16* y = (u16*)(ws);                       // LN output bf16, 32 MB
    float* x1 = (float*)(ws + 32 * MB);        // attn residual fp32, 64 MB
    u16* h = (u16*)(ws + 96 * MB);             // FF hidden bf16, 128 MB (96..224)
    u16* z = h;                                // projection bf16, 32 MB (96..128; dies before h written)
    // scan scratch lives in the h region beyond z (dead until FF1 writes h in step 5):
    float* Wbuf = (float*)(ws + 160 * MB);     // chunk weighted sums, 1 MB
    float* Rbuf = (float*)(ws + 162 * MB);     // chunk carries, 1 MB
    u16* wb_lin = (u16*)(ws + 224 * MB);       // bf16 weights
    u16* wb1 = (u16*)(ws + 225 * MB);
    u16* wb2 = (u16*)(ws + 228 * MB);

    // 0) convert weights fp32 -> bf16
    cvt_kernel<<<(DMODEL * DMODEL) / 1024, 256, 0, stream>>>(w_lin, wb_lin, DMODEL * DMODEL);
    cvt_kernel<<<(FFDIM * DMODEL) / 1024, 256, 0, stream>>>(w1, wb1, FFDIM * DMODEL);
    cvt_kernel<<<(DMODEL * FFDIM) / 1024, 256, 0, stream>>>(w2, wb2, DMODEL * FFDIM);

    // 1) y = LN(x; g1, be1)
    ln_kernel<<<NTOK / 4, 256, 0, stream>>>(x, g1, be1, y);
    // 2) z = y @ w_lin^T + b_lin
    gemm8p<0, false><<<dim3(NTOK / BM, DMODEL / BN), 512, 0, stream>>>(y, wb_lin, b_lin, nullptr,
                                                                      z, NTOK, DMODEL, DMODEL);
    // 3) x1 = x + W @ z   (carry-split exp-decay scan, exact)
    wsum_kernel<<<dim3(NCOLU / 256, NCHUNK), 256, 0, stream>>>(z, Wbuf);
    carry_kernel<<<8192 / 256, 256, 0, stream>>>(Wbuf, Rbuf);
    scan_kernel<<<dim3(NCOLU / 256, NCHUNK), 256, 0, stream>>>(z, x, Rbuf, x1);
    // 4) y = LN(x1; g2, be2)
    ln_kernel<<<NTOK / 4, 256, 0, stream>>>(x1, g2, be2, y);
    // 5) h = relu(y @ w1^T + b1)
    gemm8p<1, false><<<dim3(NTOK / BM, FFDIM / BN), 512, 0, stream>>>(y, wb1, b1, nullptr, h,
                                                                     NTOK, FFDIM, DMODEL);
    // 6) out = x1 + h @ w2^T + b2
    gemm8p<2, true><<<dim3(NTOK / BM, DMODEL / BN), 512, 0, stream>>>(h, wb2, b2, x1, out,
                                                                     NTOK, DMODEL, FFDIM);
}